// Round 15
// baseline (250.913 us; speedup 1.0000x reference)
//
#include <hip/hip_runtime.h>
#include <hip/hip_bf16.h>
#include <math.h>

// ---------------- constants ----------------
#define NNODES 50000
#define NH1    8
#define FH1    32
#define NH2    1
#define FH2    64

typedef __bf16 bf16x8 __attribute__((ext_vector_type(8)));
typedef float  f32x4  __attribute__((ext_vector_type(4)));
typedef float  f32x2  __attribute__((ext_vector_type(2)));
typedef float  ef4    __attribute__((ext_vector_type(4)));   // for nontemporal builtins

__device__ __forceinline__ ushort f2b(float f) {
    unsigned u = __float_as_uint(f);
    return (ushort)((u + 0x7fffu + ((u >> 16) & 1u)) >> 16);  // RNE
}
__device__ __forceinline__ float blo(unsigned u) { return __uint_as_float(u << 16); }
__device__ __forceinline__ float bhi(unsigned u) { return __uint_as_float(u & 0xffff0000u); }

// async global->LDS, 16B per lane (linear dest: wave-uniform base + lane*16)
__device__ __forceinline__ void gload16(void* lds, const void* g) {
    __builtin_amdgcn_global_load_lds(
        (const __attribute__((address_space(1))) void*)g,
        (__attribute__((address_space(3))) void*)lds, 16, 0, 0);
}

// ---------------- shared device helper: edge bucket fill ----------------
__device__ __forceinline__ void fill_edges4(const int* __restrict__ src,
                                            const int* __restrict__ dst,
                                            int* __restrict__ fill,
                                            int* __restrict__ colsrc, int E, int fb) {
    int i = (fb * 256 + threadIdx.x) * 4;
    if (i + 3 < E) {
        int4 d = *(const int4*)(dst + i);
        int4 s = *(const int4*)(src + i);
        colsrc[atomicAdd(&fill[d.x], 1)] = s.x;
        colsrc[atomicAdd(&fill[d.y], 1)] = s.y;
        colsrc[atomicAdd(&fill[d.z], 1)] = s.z;
        colsrc[atomicAdd(&fill[d.w], 1)] = s.w;
    } else {
        for (; i < E; ++i) colsrc[atomicAdd(&fill[dst[i]], 1)] = src[i];
    }
}

// ---------------- fused prep: feature cast + weight transposes + dst histogram ----------------
// counts must be zeroed (hipMemsetAsync) BEFORE this kernel.
#define PREP_F   12500                 // n*256/4 float4 / 256
#define PREP_W   (PREP_F + 384)        // 98304 weight elems / 256
__global__ void prep(const float* __restrict__ feat, ushort* __restrict__ fbf,
                     const float* __restrict__ W1, const float* __restrict__ W2,
                     const float* __restrict__ resW2, ushort* __restrict__ w1t,
                     ushort* __restrict__ w2t, const int* __restrict__ dst,
                     int* __restrict__ counts, int E) {
    int b = blockIdx.x;
    if (b < PREP_F) {
        int i = b * 256 + threadIdx.x;
        ef4 v = __builtin_nontemporal_load((const ef4*)feat + i);
        ushort4 o;
        o.x = f2b(v[0]); o.y = f2b(v[1]); o.z = f2b(v[2]); o.w = f2b(v[3]);
        ((ushort4*)fbf)[i] = o;
    } else if (b < PREP_W) {
        int i = (b - PREP_F) * 256 + threadIdx.x;
        if (i < 65536) {
            int nn = i >> 8, k = i & 255;
            w1t[i] = f2b(W1[k * 256 + nn]);
        } else {
            int j = i - 65536; int nn = j >> 8, k = j & 255;
            if (i < 65536 + 16384) w2t[j] = f2b(W2[k * 64 + nn]);
            else { j -= 16384; nn = j >> 8; k = j & 255; w2t[16384 + j] = f2b(resW2[k * 64 + nn]); }
        }
    } else {
        int i = ((b - PREP_W) * 256 + threadIdx.x) * 4;
        if (i + 3 < E) {
            int4 d = *(const int4*)(dst + i);
            atomicAdd(&counts[d.x], 1);
            atomicAdd(&counts[d.y], 1);
            atomicAdd(&counts[d.z], 1);
            atomicAdd(&counts[d.w], 1);
        } else {
            for (; i < E; ++i) atomicAdd(&counts[dst[i]], 1);
        }
    }
}

// ---------------- MFMA bf16 GEMM (BK=64, 33 KB LDS) + fused el/er (+ edge-fill) ----------------
// C[M,N] = A[M,K] @ Bt[N,K]^T. 128x128 tile, BK=64, 4 waves, 4+ blocks/CU.
// blocks [0, gemmNB): GEMM, bm=(b/NXB)*128, bn=(b%NXB)*128; blocks >= gemmNB: bucket fill.
// EPI 0: C -> bf16 Cb[M][N]; el/er[r*8+head]. EPI 1: cols 0-63 -> Cb + el/er; 64-127 -> Cfb.
template <int EPI, int NXB>
__global__ __launch_bounds__(256) void mfma_gemm(
    const ushort* __restrict__ A, const ushort* __restrict__ Bt,
    int M, int N, int K,
    ushort* __restrict__ Cb, ushort* __restrict__ Cfb,
    const float* __restrict__ al, const float* __restrict__ ar,
    float* __restrict__ el, float* __restrict__ er,
    int gemmNB, const int* __restrict__ esrc, const int* __restrict__ edst,
    int* __restrict__ fillp, int* __restrict__ colsrc, int E) {
    if ((int)blockIdx.x >= gemmNB) {          // fused edge-bucket fill (no LDS -> co-schedules)
        fill_edges4(esrc, edst, fillp, colsrc, E, blockIdx.x - gemmNB);
        return;
    }
    constexpr int BM = 128, BN = 128, BK = 64;
    __shared__ ushort smem[2 * BM * BK];   // 32 KB (staging, reused as C patches)
    __shared__ float alv[128], arv[128];
    ushort* As = smem;
    ushort* Bs = smem + BM * BK;
    const int bm = (blockIdx.x / NXB) * BM;
    const int bn = (blockIdx.x % NXB) * BN;
    const int tid = threadIdx.x;
    const int lane = tid & 63;
    const int wave = tid >> 6;
    const int wr = (wave >> 1) * 64;
    const int wc = (wave & 1) * 64;

    if (tid < 128) {
        if (EPI == 0) { alv[tid] = al[bn + tid];               arv[tid] = ar[bn + tid]; }
        else          { alv[tid] = (tid < 64) ? al[tid] : 0.f; arv[tid] = (tid < 64) ? ar[tid] : 0.f; }
    }

    const int rl = lane >> 3, ckl = lane & 7;
    const int swc = ckl ^ rl;              // pre-swizzled source chunk
    const ushort* gA[4]; const ushort* gB[4];
    ushort* lA[4]; ushort* lB[4];
    #pragma unroll
    for (int i = 0; i < 4; ++i) {
        int ra = bm + wave * 32 + i * 8 + rl; if (ra > M - 1) ra = M - 1;
        int rb = bn + wave * 32 + i * 8 + rl;
        gA[i] = A + (size_t)ra * K + swc * 8;
        gB[i] = Bt + (size_t)rb * K + swc * 8;
        lA[i] = As + (wave * 32 + i * 8) * BK;
        lB[i] = Bs + (wave * 32 + i * 8) * BK;
    }

    f32x4 acc[4][4];
    #pragma unroll
    for (int m = 0; m < 4; ++m)
        #pragma unroll
        for (int n = 0; n < 4; ++n)
            acc[m][n] = (f32x4){0.f, 0.f, 0.f, 0.f};

    for (int k0 = 0; k0 < K; k0 += BK) {
        __syncthreads();
        #pragma unroll
        for (int i = 0; i < 4; ++i) {
            gload16(lA[i], gA[i] + k0);
            gload16(lB[i], gB[i] + k0);
        }
        __syncthreads();
        #pragma unroll
        for (int ks = 0; ks < 2; ++ks) {
            bf16x8 af[4], bf[4];
            #pragma unroll
            for (int m = 0; m < 4; ++m) {
                int row = wr + m * 16 + (lane & 15);
                int ck = ks * 4 + (lane >> 4);
                int sw = ck ^ (row & 7);
                af[m] = *(const bf16x8*)(&As[row * BK + sw * 8]);
            }
            #pragma unroll
            for (int n = 0; n < 4; ++n) {
                int row = wc + n * 16 + (lane & 15);
                int ck = ks * 4 + (lane >> 4);
                int sw = ck ^ (row & 7);
                bf[n] = *(const bf16x8*)(&Bs[row * BK + sw * 8]);
            }
            #pragma unroll
            for (int m = 0; m < 4; ++m)
                #pragma unroll
                for (int n = 0; n < 4; ++n)
                    acc[m][n] = __builtin_amdgcn_mfma_f32_16x16x32_bf16(af[m], bf[n], acc[m][n], 0, 0, 0);
        }
    }

    __syncthreads();

    // C/D frag layout: col=lane&15, row=(lane>>4)*4+j
    {
        ushort* patch = smem + wave * 4096;
        #pragma unroll
        for (int m = 0; m < 4; ++m)
            #pragma unroll
            for (int n = 0; n < 4; ++n)
                #pragma unroll
                for (int j = 0; j < 4; ++j)
                    patch[(m * 16 + (lane >> 4) * 4 + j) * 64 + n * 16 + (lane & 15)] =
                        f2b(acc[m][n][j]);

        ushort* dstp;
        int NOUT, cb0;
        if (EPI == 0) { dstp = Cb; NOUT = N; cb0 = bn + wc; }
        else          { dstp = (wc == 0) ? Cb : Cfb; NOUT = 64; cb0 = 0; }
        #pragma unroll
        for (int i = 0; i < 8; ++i) {
            int rloc = i * 8 + (lane >> 3);
            int r = bm + wr + rloc;
            if (r < M)
                *(uint4*)(dstp + (size_t)r * NOUT + cb0 + (lane & 7) * 8) =
                    *(const uint4*)(patch + rloc * 64 + (lane & 7) * 8);
        }

        // fused el/er from the patch
        if (EPI == 0 || wc == 0) {
            int gr = bm + wr + lane;
            if (gr < M) {
                float s0 = 0.f, s1 = 0.f, t0 = 0.f, t1 = 0.f;
                #pragma unroll
                for (int c4 = 0; c4 < 16; ++c4) {
                    uint2 v = *(const uint2*)(patch + lane * 64 + c4 * 4);
                    int lc = (EPI == 0 ? wc : 0) + c4 * 4;
                    float x0 = blo(v.x), x1 = bhi(v.x), x2 = blo(v.y), x3 = bhi(v.y);
                    float d = x0 * alv[lc] + x1 * alv[lc + 1] + x2 * alv[lc + 2] + x3 * alv[lc + 3];
                    float e = x0 * arv[lc] + x1 * arv[lc + 1] + x2 * arv[lc + 2] + x3 * arv[lc + 3];
                    if (c4 < 8) { s0 += d; t0 += e; } else { s1 += d; t1 += e; }
                }
                if (EPI == 0) {
                    int hb = (bn + wc) >> 5;
                    el[gr * 8 + hb] = s0; el[gr * 8 + hb + 1] = s1;
                    er[gr * 8 + hb] = t0; er[gr * 8 + hb + 1] = t1;
                } else {
                    el[gr] = s0 + s1;
                    er[gr] = t0 + t1;
                }
            }
        }
    }
}

// ---------------- CSR scans ----------------
__global__ void scan1(const int* __restrict__ counts, int* __restrict__ bsum, int n) {
    __shared__ int red[256];
    int i = blockIdx.x * 256 + threadIdx.x;
    red[threadIdx.x] = (i < n) ? counts[i] : 0;
    __syncthreads();
    #pragma unroll
    for (int off = 128; off >= 1; off >>= 1) {
        if (threadIdx.x < off) red[threadIdx.x] += red[threadIdx.x + off];
        __syncthreads();
    }
    if (threadIdx.x == 0) bsum[blockIdx.x] = red[0];
}

// merged scan2+scan3
__global__ void scan23(const int* __restrict__ counts, const int* __restrict__ bsum,
                       int* __restrict__ rowptr, int* __restrict__ fillp, int nb, int n) {
    __shared__ int bs[256];
    __shared__ int lds[256];
    int bv = (threadIdx.x < nb) ? bsum[threadIdx.x] : 0;
    bs[threadIdx.x] = bv;
    __syncthreads();
    #pragma unroll
    for (int off = 1; off < 256; off <<= 1) {
        int t = (threadIdx.x >= off) ? bs[threadIdx.x - off] : 0;
        __syncthreads();
        bs[threadIdx.x] += t;
        __syncthreads();
    }
    int boff = (blockIdx.x > 0) ? bs[blockIdx.x - 1] : 0;
    if (blockIdx.x == 0 && threadIdx.x == 0) rowptr[n] = bs[nb - 1];

    int i = blockIdx.x * 256 + threadIdx.x;
    int v = (i < n) ? counts[i] : 0;
    lds[threadIdx.x] = v;
    __syncthreads();
    #pragma unroll
    for (int off = 1; off < 256; off <<= 1) {
        int t = (threadIdx.x >= off) ? lds[threadIdx.x - off] : 0;
        __syncthreads();
        lds[threadIdx.x] += t;
        __syncthreads();
    }
    if (i < n) {
        int ex = lds[threadIdx.x] - v + boff;
        rowptr[i] = ex;
        fillp[i] = ex;
    }
}

// ---------------- layer-1 aggregate: one WAVE per node, single pass (no max) ----------------
__global__ __launch_bounds__(256) void gat_agg1(
    const int* __restrict__ rowptr, const int* __restrict__ colsrc,
    const ushort* __restrict__ hfeat, const float* __restrict__ el,
    const float* __restrict__ er, const ushort* __restrict__ resv,
    const float* __restrict__ bias, ushort* __restrict__ out) {
    const int lane = threadIdx.x & 63;
    const int node = blockIdx.x * 4 + (threadIdx.x >> 6);
    const int r0 = rowptr[node], r1 = rowptr[node + 1];
    const int e8 = lane >> 3, hs = lane & 7;
    const float eri = er[node * 8 + hs];

    const int half = lane >> 5;
    const int l5 = lane & 31;
    const int hf = l5 >> 2, fb = l5 & 3;
    const ushort* __restrict__ fbase = hfeat + hf * 32 + fb * 8;
    const int pbase = half * 8 + hf;

    float wsum = 0.f;
    f32x2 a01 = {0.f, 0.f}, a23 = {0.f, 0.f}, a45 = {0.f, 0.f}, a67 = {0.f, 0.f};
    #pragma unroll 2
    for (int b = r0; b < r1; b += 8) {
        int idx = b + e8;
        int s = 0; float a = 0.f;
        if (idx < r1) {
            s = colsrc[idx];
            float x = el[s * 8 + hs] + eri;
            x = fmaxf(x, 0.2f * x);          // leaky relu
            a = __expf(x);
        }
        wsum += a;
        #pragma unroll
        for (int e = 0; e < 8; e += 2) {
            int pi = pbase + e * 8;
            int si = __shfl(s, pi);
            float we = __shfl(a, pi);
            uint4 v = *(const uint4*)(fbase + ((size_t)(unsigned)si << 8));
            f32x2 w2 = {we, we};
            a01 += w2 * (f32x2){blo(v.x), bhi(v.x)};
            a23 += w2 * (f32x2){blo(v.y), bhi(v.y)};
            a45 += w2 * (f32x2){blo(v.z), bhi(v.z)};
            a67 += w2 * (f32x2){blo(v.w), bhi(v.w)};
        }
    }
    wsum += __shfl_xor(wsum, 8);
    wsum += __shfl_xor(wsum, 16);
    wsum += __shfl_xor(wsum, 32);
    float dn = __shfl(wsum, hf);

    a01.x += __shfl_xor(a01.x, 32); a01.y += __shfl_xor(a01.y, 32);
    a23.x += __shfl_xor(a23.x, 32); a23.y += __shfl_xor(a23.y, 32);
    a45.x += __shfl_xor(a45.x, 32); a45.y += __shfl_xor(a45.y, 32);
    a67.x += __shfl_xor(a67.x, 32); a67.y += __shfl_xor(a67.y, 32);

    float f0, f1, f2, f3;
    if (half == 0) { f0 = a01.x; f1 = a01.y; f2 = a23.x; f3 = a23.y; }
    else           { f0 = a45.x; f1 = a45.y; f2 = a67.x; f3 = a67.y; }
    int fo = hf * 32 + fb * 8 + half * 4;
    int ob = node * 256 + fo;
    uint2 rv = *(const uint2*)(resv + ob);       // bf16 residual
    ef4 bv = *(const ef4*)(bias + fo);
    float o0 = f0 / dn + blo(rv.x) + bv[0];
    float o1 = f1 / dn + bhi(rv.x) + bv[1];
    float o2 = f2 / dn + blo(rv.y) + bv[2];
    float o3 = f3 / dn + bhi(rv.y) + bv[3];
    o0 = (o0 > 0.f) ? o0 : expm1f(o0);
    o1 = (o1 > 0.f) ? o1 : expm1f(o1);
    o2 = (o2 > 0.f) ? o2 : expm1f(o2);
    o3 = (o3 > 0.f) ? o3 : expm1f(o3);
    ushort4 st; st.x = f2b(o0); st.y = f2b(o1); st.z = f2b(o2); st.w = f2b(o3);
    *(ushort4*)(out + ob) = st;
}

// ---------------- layer-2 aggregate: one WAVE per node, single pass (no max) ----------------
__global__ __launch_bounds__(256) void gat_agg2(
    const int* __restrict__ rowptr, const int* __restrict__ colsrc,
    const ushort* __restrict__ hfeat, const float* __restrict__ el,
    const float* __restrict__ er, const ushort* __restrict__ resv,
    const float* __restrict__ bias, float* __restrict__ out) {
    const int lane = threadIdx.x & 63;
    const int node = blockIdx.x * 4 + (threadIdx.x >> 6);
    const int r0 = rowptr[node], r1 = rowptr[node + 1];
    const float eri = er[node];
    const int e8 = lane >> 3, f8 = lane & 7;
    const ushort* __restrict__ fbase = hfeat + f8 * 8;

    float wsum = 0.f;
    f32x2 a01 = {0.f, 0.f}, a23 = {0.f, 0.f}, a45 = {0.f, 0.f}, a67 = {0.f, 0.f};
    for (int b = r0; b < r1; b += 64) {
        int idx = b + lane;
        int s = 0; float a = 0.f;
        if (idx < r1) {
            s = colsrc[idx];
            float x = el[s] + eri;
            x = fmaxf(x, 0.2f * x);
            a = __expf(x);
        }
        wsum += a;
        int nn = min(64, r1 - b);
        #pragma unroll 4
        for (int t = 0; t < nn; t += 8) {
            int pi = t + e8;
            int si = __shfl(s, pi);
            float we = __shfl(a, pi);
            uint4 v = *(const uint4*)(fbase + ((size_t)(unsigned)si << 6));
            f32x2 w2 = {we, we};
            a01 += w2 * (f32x2){blo(v.x), bhi(v.x)};
            a23 += w2 * (f32x2){blo(v.y), bhi(v.y)};
            a45 += w2 * (f32x2){blo(v.z), bhi(v.z)};
            a67 += w2 * (f32x2){blo(v.w), bhi(v.w)};
        }
    }
    #pragma unroll
    for (int m = 1; m < 64; m <<= 1) wsum += __shfl_xor(wsum, m);
    #pragma unroll
    for (int m = 8; m < 64; m <<= 1) {
        a01.x += __shfl_xor(a01.x, m); a01.y += __shfl_xor(a01.y, m);
        a23.x += __shfl_xor(a23.x, m); a23.y += __shfl_xor(a23.y, m);
        a45.x += __shfl_xor(a45.x, m); a45.y += __shfl_xor(a45.y, m);
        a67.x += __shfl_xor(a67.x, m); a67.y += __shfl_xor(a67.y, m);
    }

    if (e8 == 0) {
        int ob = node * 64 + f8 * 8;
        uint4 rv = *(const uint4*)(resv + ob);   // 8 bf16 residuals
        ef4 bv0 = *(const ef4*)(bias + f8 * 8);
        ef4 bv1 = *(const ef4*)(bias + f8 * 8 + 4);
        ef4 o0, o1;
        float rw = 1.f / wsum;
        o0[0] = a01.x * rw + blo(rv.x) + bv0[0];
        o0[1] = a01.y * rw + bhi(rv.x) + bv0[1];
        o0[2] = a23.x * rw + blo(rv.y) + bv0[2];
        o0[3] = a23.y * rw + bhi(rv.y) + bv0[3];
        o1[0] = a45.x * rw + blo(rv.z) + bv1[0];
        o1[1] = a45.y * rw + bhi(rv.z) + bv1[1];
        o1[2] = a67.x * rw + blo(rv.w) + bv1[2];
        o1[3] = a67.y * rw + bhi(rv.w) + bv1[3];
        __builtin_nontemporal_store(o0, (ef4*)(out + ob));
        __builtin_nontemporal_store(o1, (ef4*)(out + ob + 4));
    }
}

extern "C" void kernel_launch(void* const* d_in, const int* in_sizes, int n_in,
                              void* d_out, int out_size, void* d_ws, size_t ws_size,
                              hipStream_t stream) {
    const float* features = (const float*)d_in[0];
    const int*   src      = (const int*)d_in[1];
    const int*   dst      = (const int*)d_in[2];
    const float* W1       = (const float*)d_in[3];
    const float* attn_l1  = (const float*)d_in[4];
    const float* attn_r1  = (const float*)d_in[5];
    const float* bias1    = (const float*)d_in[6];
    const float* W2       = (const float*)d_in[7];
    const float* attn_l2  = (const float*)d_in[8];
    const float* attn_r2  = (const float*)d_in[9];
    const float* bias2    = (const float*)d_in[10];
    const float* resW2    = (const float*)d_in[11];
    const int E = in_sizes[1];
    const int n = NNODES;
    const int nb = (n + 255) / 256;
    const int histNB = (E + 1023) / 1024;

    // workspace carve-up
    ushort* fbf  = (ushort*)d_ws;                 // n*256 bf16
    ushort* h1bf = fbf  + (size_t)n * 256;        // n*256 bf16
    ushort* x1bf = h1bf + (size_t)n * 256;        // n*256 bf16
    ushort* h2bf = x1bf + (size_t)n * 256;        // n*64 bf16
    ushort* res2 = h2bf + (size_t)n * 64;         // n*64 bf16
    ushort* w1t  = res2 + (size_t)n * 64;         // 256*256
    ushort* w2t  = w1t + 256 * 256;               // 128*256
    float*  el1  = (float*)(w2t + 128 * 256);     // n*8
    float*  er1  = el1 + (size_t)n * NH1;         // n*8
    float*  el2  = er1 + (size_t)n * NH1;         // n
    float*  er2  = el2 + n;                       // n
    int* counts  = (int*)(er2 + n);               // n
    int* rowptr  = counts + n;                    // n+1
    int* fillp   = rowptr + n + 1;                // n
    int* bsum    = fillp + n;                     // nb
    int* colsrc  = bsum + nb;                     // E

    // ---- fused prep: cast + transposes + dst histogram (counts pre-zeroed) ----
    hipMemsetAsync(counts, 0, (size_t)n * 4, stream);
    prep<<<PREP_W + histNB, 256, 0, stream>>>(features, fbf, W1, W2, resW2, w1t, w2t,
                                              dst, counts, E);

    // ---- CSR scans ----
    scan1<<<nb, 256, 0, stream>>>(counts, bsum, n);
    scan23<<<nb, 256, 0, stream>>>(counts, bsum, rowptr, fillp, nb, n);

    // ---- layer 1 GEMM (+ fused edge-bucket fill) ----
    const int gemmNB1 = 2 * ((n + 127) / 128);
    mfma_gemm<0, 2><<<gemmNB1 + histNB, 256, 0, stream>>>(
        fbf, w1t, n, 256, 256, h1bf, nullptr, attn_l1, attn_r1, el1, er1,
        gemmNB1, src, dst, fillp, colsrc, E);
    gat_agg1<<<(n + 3) / 4, 256, 0, stream>>>(rowptr, colsrc, h1bf, el1, er1, fbf, bias1, x1bf);

    // ---- layer 2 (W2 and resW2 fused into one N=128 GEMM) ----
    const int gemmNB2 = (n + 127) / 128;
    mfma_gemm<1, 1><<<gemmNB2, 256, 0, stream>>>(
        x1bf, w2t, n, 128, 256, h2bf, res2, attn_l2, attn_r2, el2, er2,
        gemmNB2, nullptr, nullptr, nullptr, nullptr, 0);
    gat_agg2<<<(n + 3) / 4, 256, 0, stream>>>(rowptr, colsrc, h2bf, el2, er2, res2, bias2, (float*)d_out);
}

// Round 16
// 234.196 us; speedup vs baseline: 1.0714x; 1.0714x over previous
//
#include <hip/hip_runtime.h>
#include <hip/hip_bf16.h>
#include <math.h>

// ---------------- constants ----------------
#define NNODES 50000
#define NH1    8
#define FH1    32
#define NH2    1
#define FH2    64

typedef __bf16 bf16x8 __attribute__((ext_vector_type(8)));
typedef float  f32x4  __attribute__((ext_vector_type(4)));
typedef float  f32x2  __attribute__((ext_vector_type(2)));
typedef float  ef4    __attribute__((ext_vector_type(4)));   // for nontemporal builtins

__device__ __forceinline__ ushort f2b(float f) {
    unsigned u = __float_as_uint(f);
    return (ushort)((u + 0x7fffu + ((u >> 16) & 1u)) >> 16);  // RNE
}
__device__ __forceinline__ float blo(unsigned u) { return __uint_as_float(u << 16); }
__device__ __forceinline__ float bhi(unsigned u) { return __uint_as_float(u & 0xffff0000u); }

// async global->LDS, 16B per lane (linear dest: wave-uniform base + lane*16)
__device__ __forceinline__ void gload16(void* lds, const void* g) {
    __builtin_amdgcn_global_load_lds(
        (const __attribute__((address_space(1))) void*)g,
        (__attribute__((address_space(3))) void*)lds, 16, 0, 0);
}

// ---------------- shared device helper: edge bucket fill ----------------
__device__ __forceinline__ void fill_edges4(const int* __restrict__ src,
                                            const int* __restrict__ dst,
                                            int* __restrict__ fill,
                                            int* __restrict__ colsrc, int E, int fb) {
    int i = (fb * 256 + threadIdx.x) * 4;
    if (i + 3 < E) {
        int4 d = *(const int4*)(dst + i);
        int4 s = *(const int4*)(src + i);
        colsrc[atomicAdd(&fill[d.x], 1)] = s.x;
        colsrc[atomicAdd(&fill[d.y], 1)] = s.y;
        colsrc[atomicAdd(&fill[d.z], 1)] = s.z;
        colsrc[atomicAdd(&fill[d.w], 1)] = s.w;
    } else {
        for (; i < E; ++i) colsrc[atomicAdd(&fill[dst[i]], 1)] = src[i];
    }
}

// ---------------- fused prep: cast + transposes + histogram + W2-attn folds ----------------
// counts must be zeroed (hipMemsetAsync) BEFORE this kernel.
// blocks [0,PREP_F): feature cast; [PREP_F,PREP_W): weight transposes;
// [PREP_W, gridDim-1): dst histogram; last block: w2v[k] = (W2[k,:]·al2, W2[k,:]·ar2).
#define PREP_F   12500                 // n*256/4 float4 / 256
#define PREP_W   (PREP_F + 384)        // 98304 weight elems / 256
__global__ void prep(const float* __restrict__ feat, ushort* __restrict__ fbf,
                     const float* __restrict__ W1, const float* __restrict__ W2,
                     const float* __restrict__ resW2, ushort* __restrict__ w1t,
                     ushort* __restrict__ w2t, const int* __restrict__ dst,
                     int* __restrict__ counts, int E,
                     const float* __restrict__ al2, const float* __restrict__ ar2,
                     float2* __restrict__ w2v) {
    int b = blockIdx.x;
    if (b < PREP_F) {
        int i = b * 256 + threadIdx.x;
        ef4 v = __builtin_nontemporal_load((const ef4*)feat + i);
        ushort4 o;
        o.x = f2b(v[0]); o.y = f2b(v[1]); o.z = f2b(v[2]); o.w = f2b(v[3]);
        ((ushort4*)fbf)[i] = o;
    } else if (b < PREP_W) {
        int i = (b - PREP_F) * 256 + threadIdx.x;
        if (i < 65536) {
            int nn = i >> 8, k = i & 255;
            w1t[i] = f2b(W1[k * 256 + nn]);
        } else {
            int j = i - 65536; int nn = j >> 8, k = j & 255;
            if (i < 65536 + 16384) w2t[j] = f2b(W2[k * 64 + nn]);
            else { j -= 16384; nn = j >> 8; k = j & 255; w2t[16384 + j] = f2b(resW2[k * 64 + nn]); }
        }
    } else if (b == (int)gridDim.x - 1) {
        int k = threadIdx.x;                 // 0..255
        float sl = 0.f, sr = 0.f;
        #pragma unroll 8
        for (int c = 0; c < 64; ++c) {
            float w = W2[k * 64 + c];
            sl += w * al2[c];
            sr += w * ar2[c];
        }
        w2v[k] = make_float2(sl, sr);
    } else {
        int i = ((b - PREP_W) * 256 + threadIdx.x) * 4;
        if (i + 3 < E) {
            int4 d = *(const int4*)(dst + i);
            atomicAdd(&counts[d.x], 1);
            atomicAdd(&counts[d.y], 1);
            atomicAdd(&counts[d.z], 1);
            atomicAdd(&counts[d.w], 1);
        } else {
            for (; i < E; ++i) atomicAdd(&counts[dst[i]], 1);
        }
    }
}

// ---------------- MFMA bf16 GEMM (BK=64, 33 KB LDS) + fused el/er (+ edge-fill) ----------------
// C[M,N] = A[M,K] @ Bt[N,K]^T. 128x128 tile, BK=64, 4 waves, 4+ blocks/CU.
// blocks [0, gemmNB): GEMM; blocks >= gemmNB: bucket fill.
// EPI 0: C -> bf16 Cb[M][N]; el/er[r*8+head] from patch.
// EPI 1: cols 0-63 -> bf16 Cb[M][64]; cols 64-127 -> bf16 Cfb[M][64]; NO el/er.
template <int EPI, int NXB>
__global__ __launch_bounds__(256) void mfma_gemm(
    const ushort* __restrict__ A, const ushort* __restrict__ Bt,
    int M, int N, int K,
    ushort* __restrict__ Cb, ushort* __restrict__ Cfb,
    const float* __restrict__ al, const float* __restrict__ ar,
    float* __restrict__ el, float* __restrict__ er,
    int gemmNB, const int* __restrict__ esrc, const int* __restrict__ edst,
    int* __restrict__ fillp, int* __restrict__ colsrc, int E) {
    if ((int)blockIdx.x >= gemmNB) {          // fused edge-bucket fill (no LDS -> co-schedules)
        fill_edges4(esrc, edst, fillp, colsrc, E, blockIdx.x - gemmNB);
        return;
    }
    constexpr int BM = 128, BN = 128, BK = 64;
    __shared__ ushort smem[2 * BM * BK];   // 32 KB (staging, reused as C patches)
    __shared__ float alv[128], arv[128];
    ushort* As = smem;
    ushort* Bs = smem + BM * BK;
    const int bm = (blockIdx.x / NXB) * BM;
    const int bn = (blockIdx.x % NXB) * BN;
    const int tid = threadIdx.x;
    const int lane = tid & 63;
    const int wave = tid >> 6;
    const int wr = (wave >> 1) * 64;
    const int wc = (wave & 1) * 64;

    if (EPI == 0 && tid < 128) {
        alv[tid] = al[bn + tid];
        arv[tid] = ar[bn + tid];
    }

    const int rl = lane >> 3, ckl = lane & 7;
    const int swc = ckl ^ rl;              // pre-swizzled source chunk
    const ushort* gA[4]; const ushort* gB[4];
    ushort* lA[4]; ushort* lB[4];
    #pragma unroll
    for (int i = 0; i < 4; ++i) {
        int ra = bm + wave * 32 + i * 8 + rl; if (ra > M - 1) ra = M - 1;
        int rb = bn + wave * 32 + i * 8 + rl;
        gA[i] = A + (size_t)ra * K + swc * 8;
        gB[i] = Bt + (size_t)rb * K + swc * 8;
        lA[i] = As + (wave * 32 + i * 8) * BK;
        lB[i] = Bs + (wave * 32 + i * 8) * BK;
    }

    f32x4 acc[4][4];
    #pragma unroll
    for (int m = 0; m < 4; ++m)
        #pragma unroll
        for (int n = 0; n < 4; ++n)
            acc[m][n] = (f32x4){0.f, 0.f, 0.f, 0.f};

    for (int k0 = 0; k0 < K; k0 += BK) {
        __syncthreads();
        #pragma unroll
        for (int i = 0; i < 4; ++i) {
            gload16(lA[i], gA[i] + k0);
            gload16(lB[i], gB[i] + k0);
        }
        __syncthreads();
        #pragma unroll
        for (int ks = 0; ks < 2; ++ks) {
            bf16x8 af[4], bf[4];
            #pragma unroll
            for (int m = 0; m < 4; ++m) {
                int row = wr + m * 16 + (lane & 15);
                int ck = ks * 4 + (lane >> 4);
                int sw = ck ^ (row & 7);
                af[m] = *(const bf16x8*)(&As[row * BK + sw * 8]);
            }
            #pragma unroll
            for (int n = 0; n < 4; ++n) {
                int row = wc + n * 16 + (lane & 15);
                int ck = ks * 4 + (lane >> 4);
                int sw = ck ^ (row & 7);
                bf[n] = *(const bf16x8*)(&Bs[row * BK + sw * 8]);
            }
            #pragma unroll
            for (int m = 0; m < 4; ++m)
                #pragma unroll
                for (int n = 0; n < 4; ++n)
                    acc[m][n] = __builtin_amdgcn_mfma_f32_16x16x32_bf16(af[m], bf[n], acc[m][n], 0, 0, 0);
        }
    }

    __syncthreads();

    // C/D frag layout: col=lane&15, row=(lane>>4)*4+j
    {
        ushort* patch = smem + wave * 4096;
        #pragma unroll
        for (int m = 0; m < 4; ++m)
            #pragma unroll
            for (int n = 0; n < 4; ++n)
                #pragma unroll
                for (int j = 0; j < 4; ++j)
                    patch[(m * 16 + (lane >> 4) * 4 + j) * 64 + n * 16 + (lane & 15)] =
                        f2b(acc[m][n][j]);

        ushort* dstp;
        int NOUT, cb0;
        if (EPI == 0) { dstp = Cb; NOUT = N; cb0 = bn + wc; }
        else          { dstp = (wc == 0) ? Cb : Cfb; NOUT = 64; cb0 = 0; }
        #pragma unroll
        for (int i = 0; i < 8; ++i) {
            int rloc = i * 8 + (lane >> 3);
            int r = bm + wr + rloc;
            if (r < M)
                *(uint4*)(dstp + (size_t)r * NOUT + cb0 + (lane & 7) * 8) =
                    *(const uint4*)(patch + rloc * 64 + (lane & 7) * 8);
        }

        // fused el/er from the patch (layer 1 only; layer-2 scores come from gat_agg1)
        if (EPI == 0) {
            int gr = bm + wr + lane;
            if (gr < M) {
                float s0 = 0.f, s1 = 0.f, t0 = 0.f, t1 = 0.f;
                #pragma unroll
                for (int c4 = 0; c4 < 16; ++c4) {
                    uint2 v = *(const uint2*)(patch + lane * 64 + c4 * 4);
                    int lc = wc + c4 * 4;
                    float x0 = blo(v.x), x1 = bhi(v.x), x2 = blo(v.y), x3 = bhi(v.y);
                    float d = x0 * alv[lc] + x1 * alv[lc + 1] + x2 * alv[lc + 2] + x3 * alv[lc + 3];
                    float e = x0 * arv[lc] + x1 * arv[lc + 1] + x2 * arv[lc + 2] + x3 * arv[lc + 3];
                    if (c4 < 8) { s0 += d; t0 += e; } else { s1 += d; t1 += e; }
                }
                int hb = (bn + wc) >> 5;
                el[gr * 8 + hb] = s0; el[gr * 8 + hb + 1] = s1;
                er[gr * 8 + hb] = t0; er[gr * 8 + hb + 1] = t1;
            }
        }
    }
}

// ---------------- CSR scans ----------------
__global__ void scan1(const int* __restrict__ counts, int* __restrict__ bsum, int n) {
    __shared__ int red[256];
    int i = blockIdx.x * 256 + threadIdx.x;
    red[threadIdx.x] = (i < n) ? counts[i] : 0;
    __syncthreads();
    #pragma unroll
    for (int off = 128; off >= 1; off >>= 1) {
        if (threadIdx.x < off) red[threadIdx.x] += red[threadIdx.x + off];
        __syncthreads();
    }
    if (threadIdx.x == 0) bsum[blockIdx.x] = red[0];
}

// merged scan2+scan3
__global__ void scan23(const int* __restrict__ counts, const int* __restrict__ bsum,
                       int* __restrict__ rowptr, int* __restrict__ fillp, int nb, int n) {
    __shared__ int bs[256];
    __shared__ int lds[256];
    int bv = (threadIdx.x < nb) ? bsum[threadIdx.x] : 0;
    bs[threadIdx.x] = bv;
    __syncthreads();
    #pragma unroll
    for (int off = 1; off < 256; off <<= 1) {
        int t = (threadIdx.x >= off) ? bs[threadIdx.x - off] : 0;
        __syncthreads();
        bs[threadIdx.x] += t;
        __syncthreads();
    }
    int boff = (blockIdx.x > 0) ? bs[blockIdx.x - 1] : 0;
    if (blockIdx.x == 0 && threadIdx.x == 0) rowptr[n] = bs[nb - 1];

    int i = blockIdx.x * 256 + threadIdx.x;
    int v = (i < n) ? counts[i] : 0;
    lds[threadIdx.x] = v;
    __syncthreads();
    #pragma unroll
    for (int off = 1; off < 256; off <<= 1) {
        int t = (threadIdx.x >= off) ? lds[threadIdx.x - off] : 0;
        __syncthreads();
        lds[threadIdx.x] += t;
        __syncthreads();
    }
    if (i < n) {
        int ex = lds[threadIdx.x] - v + boff;
        rowptr[i] = ex;
        fillp[i] = ex;
    }
}

// ---------------- layer-1 aggregate: one WAVE per node + fused layer-2 scores ----------------
__global__ __launch_bounds__(256) void gat_agg1(
    const int* __restrict__ rowptr, const int* __restrict__ colsrc,
    const ushort* __restrict__ hfeat, const float* __restrict__ el,
    const float* __restrict__ er, const ushort* __restrict__ resv,
    const float* __restrict__ bias, ushort* __restrict__ out,
    const float2* __restrict__ w2v, float* __restrict__ el2, float* __restrict__ er2) {
    const int lane = threadIdx.x & 63;
    const int node = blockIdx.x * 4 + (threadIdx.x >> 6);
    const int r0 = rowptr[node], r1 = rowptr[node + 1];
    const int e8 = lane >> 3, hs = lane & 7;
    const float eri = er[node * 8 + hs];

    const int half = lane >> 5;
    const int l5 = lane & 31;
    const int hf = l5 >> 2, fb = l5 & 3;
    const ushort* __restrict__ fbase = hfeat + hf * 32 + fb * 8;
    const int pbase = half * 8 + hf;

    float wsum = 0.f;
    f32x2 a01 = {0.f, 0.f}, a23 = {0.f, 0.f}, a45 = {0.f, 0.f}, a67 = {0.f, 0.f};
    #pragma unroll 2
    for (int b = r0; b < r1; b += 8) {
        int idx = b + e8;
        int s = 0; float a = 0.f;
        if (idx < r1) {
            s = __builtin_nontemporal_load(colsrc + idx);
            float x = el[s * 8 + hs] + eri;
            x = fmaxf(x, 0.2f * x);          // leaky relu
            a = __expf(x);
        }
        wsum += a;
        #pragma unroll
        for (int e = 0; e < 8; e += 2) {
            int pi = pbase + e * 8;
            int si = __shfl(s, pi);
            float we = __shfl(a, pi);
            uint4 v = *(const uint4*)(fbase + ((size_t)(unsigned)si << 8));
            f32x2 w2 = {we, we};
            a01 += w2 * (f32x2){blo(v.x), bhi(v.x)};
            a23 += w2 * (f32x2){blo(v.y), bhi(v.y)};
            a45 += w2 * (f32x2){blo(v.z), bhi(v.z)};
            a67 += w2 * (f32x2){blo(v.w), bhi(v.w)};
        }
    }
    wsum += __shfl_xor(wsum, 8);
    wsum += __shfl_xor(wsum, 16);
    wsum += __shfl_xor(wsum, 32);
    float dn = __shfl(wsum, hf);

    a01.x += __shfl_xor(a01.x, 32); a01.y += __shfl_xor(a01.y, 32);
    a23.x += __shfl_xor(a23.x, 32); a23.y += __shfl_xor(a23.y, 32);
    a45.x += __shfl_xor(a45.x, 32); a45.y += __shfl_xor(a45.y, 32);
    a67.x += __shfl_xor(a67.x, 32); a67.y += __shfl_xor(a67.y, 32);

    float f0, f1, f2, f3;
    if (half == 0) { f0 = a01.x; f1 = a01.y; f2 = a23.x; f3 = a23.y; }
    else           { f0 = a45.x; f1 = a45.y; f2 = a67.x; f3 = a67.y; }
    int fo = hf * 32 + fb * 8 + half * 4;
    int ob = node * 256 + fo;
    uint2 rv = *(const uint2*)(resv + ob);       // bf16 residual
    ef4 bv = *(const ef4*)(bias + fo);
    float o0 = f0 / dn + blo(rv.x) + bv[0];
    float o1 = f1 / dn + bhi(rv.x) + bv[1];
    float o2 = f2 / dn + blo(rv.y) + bv[2];
    float o3 = f3 / dn + bhi(rv.y) + bv[3];
    o0 = (o0 > 0.f) ? o0 : expm1f(o0);
    o1 = (o1 > 0.f) ? o1 : expm1f(o1);
    o2 = (o2 > 0.f) ? o2 : expm1f(o2);
    o3 = (o3 > 0.f) ? o3 : expm1f(o3);
    ushort4 st; st.x = f2b(o0); st.y = f2b(o1); st.z = f2b(o2); st.w = f2b(o3);
    *(ushort4*)(out + ob) = st;

    // fused layer-2 scores: el2 = x1·(W2@al2), er2 = x1·(W2@ar2)
    float2 v0 = w2v[fo], v1 = w2v[fo + 1], v2 = w2v[fo + 2], v3 = w2v[fo + 3];
    float sl = o0 * v0.x + o1 * v1.x + o2 * v2.x + o3 * v3.x;
    float sr = o0 * v0.y + o1 * v1.y + o2 * v2.y + o3 * v3.y;
    #pragma unroll
    for (int m = 1; m < 64; m <<= 1) {
        sl += __shfl_xor(sl, m);
        sr += __shfl_xor(sr, m);
    }
    if (lane == 0) {
        el2[node] = sl;
        er2[node] = sr;
    }
}

// ---------------- layer-2 aggregate: one WAVE per node, single pass (no max) ----------------
__global__ __launch_bounds__(256) void gat_agg2(
    const int* __restrict__ rowptr, const int* __restrict__ colsrc,
    const ushort* __restrict__ hfeat, const float* __restrict__ el,
    const float* __restrict__ er, const ushort* __restrict__ resv,
    const float* __restrict__ bias, float* __restrict__ out) {
    const int lane = threadIdx.x & 63;
    const int node = blockIdx.x * 4 + (threadIdx.x >> 6);
    const int r0 = rowptr[node], r1 = rowptr[node + 1];
    const float eri = er[node];
    const int e8 = lane >> 3, f8 = lane & 7;
    const ushort* __restrict__ fbase = hfeat + f8 * 8;

    float wsum = 0.f;
    f32x2 a01 = {0.f, 0.f}, a23 = {0.f, 0.f}, a45 = {0.f, 0.f}, a67 = {0.f, 0.f};
    for (int b = r0; b < r1; b += 64) {
        int idx = b + lane;
        int s = 0; float a = 0.f;
        if (idx < r1) {
            s = __builtin_nontemporal_load(colsrc + idx);
            float x = el[s] + eri;
            x = fmaxf(x, 0.2f * x);
            a = __expf(x);
        }
        wsum += a;
        int nn = min(64, r1 - b);
        #pragma unroll 4
        for (int t = 0; t < nn; t += 8) {
            int pi = t + e8;
            int si = __shfl(s, pi);
            float we = __shfl(a, pi);
            uint4 v = *(const uint4*)(fbase + ((size_t)(unsigned)si << 6));
            f32x2 w2 = {we, we};
            a01 += w2 * (f32x2){blo(v.x), bhi(v.x)};
            a23 += w2 * (f32x2){blo(v.y), bhi(v.y)};
            a45 += w2 * (f32x2){blo(v.z), bhi(v.z)};
            a67 += w2 * (f32x2){blo(v.w), bhi(v.w)};
        }
    }
    #pragma unroll
    for (int m = 1; m < 64; m <<= 1) wsum += __shfl_xor(wsum, m);
    #pragma unroll
    for (int m = 8; m < 64; m <<= 1) {
        a01.x += __shfl_xor(a01.x, m); a01.y += __shfl_xor(a01.y, m);
        a23.x += __shfl_xor(a23.x, m); a23.y += __shfl_xor(a23.y, m);
        a45.x += __shfl_xor(a45.x, m); a45.y += __shfl_xor(a45.y, m);
        a67.x += __shfl_xor(a67.x, m); a67.y += __shfl_xor(a67.y, m);
    }

    if (e8 == 0) {
        int ob = node * 64 + f8 * 8;
        uint4 rv = *(const uint4*)(resv + ob);   // 8 bf16 residuals
        ef4 bv0 = *(const ef4*)(bias + f8 * 8);
        ef4 bv1 = *(const ef4*)(bias + f8 * 8 + 4);
        ef4 o0, o1;
        float rw = 1.f / wsum;
        o0[0] = a01.x * rw + blo(rv.x) + bv0[0];
        o0[1] = a01.y * rw + bhi(rv.x) + bv0[1];
        o0[2] = a23.x * rw + blo(rv.y) + bv0[2];
        o0[3] = a23.y * rw + bhi(rv.y) + bv0[3];
        o1[0] = a45.x * rw + blo(rv.z) + bv1[0];
        o1[1] = a45.y * rw + bhi(rv.z) + bv1[1];
        o1[2] = a67.x * rw + blo(rv.w) + bv1[2];
        o1[3] = a67.y * rw + bhi(rv.w) + bv1[3];
        __builtin_nontemporal_store(o0, (ef4*)(out + ob));
        __builtin_nontemporal_store(o1, (ef4*)(out + ob + 4));
    }
}

extern "C" void kernel_launch(void* const* d_in, const int* in_sizes, int n_in,
                              void* d_out, int out_size, void* d_ws, size_t ws_size,
                              hipStream_t stream) {
    const float* features = (const float*)d_in[0];
    const int*   src      = (const int*)d_in[1];
    const int*   dst      = (const int*)d_in[2];
    const float* W1       = (const float*)d_in[3];
    const float* attn_l1  = (const float*)d_in[4];
    const float* attn_r1  = (const float*)d_in[5];
    const float* bias1    = (const float*)d_in[6];
    const float* W2       = (const float*)d_in[7];
    const float* attn_l2  = (const float*)d_in[8];
    const float* attn_r2  = (const float*)d_in[9];
    const float* bias2    = (const float*)d_in[10];
    const float* resW2    = (const float*)d_in[11];
    const int E = in_sizes[1];
    const int n = NNODES;
    const int nb = (n + 255) / 256;
    const int histNB = (E + 1023) / 1024;

    // workspace carve-up
    ushort* fbf  = (ushort*)d_ws;                 // n*256 bf16
    ushort* h1bf = fbf  + (size_t)n * 256;        // n*256 bf16
    ushort* x1bf = h1bf + (size_t)n * 256;        // n*256 bf16
    ushort* h2bf = x1bf + (size_t)n * 256;        // n*64 bf16
    ushort* res2 = h2bf + (size_t)n * 64;         // n*64 bf16
    ushort* w1t  = res2 + (size_t)n * 64;         // 256*256
    ushort* w2t  = w1t + 256 * 256;               // 128*256
    float*  el1  = (float*)(w2t + 128 * 256);     // n*8
    float*  er1  = el1 + (size_t)n * NH1;         // n*8
    float*  el2  = er1 + (size_t)n * NH1;         // n
    float*  er2  = el2 + n;                       // n
    float2* w2v  = (float2*)(er2 + n);            // 256 float2
    int* counts  = (int*)(w2v + 256);             // n
    int* rowptr  = counts + n;                    // n+1
    int* fillp   = rowptr + n + 1;                // n
    int* bsum    = fillp + n;                     // nb
    int* colsrc  = bsum + nb;                     // E

    // ---- fused prep: cast + transposes + histogram + w2v (counts pre-zeroed) ----
    hipMemsetAsync(counts, 0, (size_t)n * 4, stream);
    prep<<<PREP_W + histNB + 1, 256, 0, stream>>>(features, fbf, W1, W2, resW2, w1t, w2t,
                                                  dst, counts, E, attn_l2, attn_r2, w2v);

    // ---- CSR scans ----
    scan1<<<nb, 256, 0, stream>>>(counts, bsum, n);
    scan23<<<nb, 256, 0, stream>>>(counts, bsum, rowptr, fillp, nb, n);

    // ---- layer 1 GEMM (+ fused edge-bucket fill) ----
    const int gemmNB1 = 2 * ((n + 127) / 128);
    mfma_gemm<0, 2><<<gemmNB1 + histNB, 256, 0, stream>>>(
        fbf, w1t, n, 256, 256, h1bf, nullptr, attn_l1, attn_r1, el1, er1,
        gemmNB1, src, dst, fillp, colsrc, E);
    gat_agg1<<<(n + 3) / 4, 256, 0, stream>>>(rowptr, colsrc, h1bf, el1, er1, fbf, bias1, x1bf,
                                              w2v, el2, er2);

    // ---- layer 2 (W2 and resW2 fused into one N=128 GEMM; scores already computed) ----
    const int gemmNB2 = (n + 127) / 128;
    mfma_gemm<1, 1><<<gemmNB2, 256, 0, stream>>>(
        x1bf, w2t, n, 128, 256, h2bf, res2, nullptr, nullptr, nullptr, nullptr,
        gemmNB2, nullptr, nullptr, nullptr, nullptr, 0);
    gat_agg2<<<(n + 3) / 4, 256, 0, stream>>>(rowptr, colsrc, h2bf, el2, er2, res2, bias2, (float*)d_out);
}